// Round 8
// baseline (773.811 us; speedup 1.0000x reference)
//
#include <hip/hip_runtime.h>

#define NT 1024

typedef __attribute__((ext_vector_type(8))) short short8;
typedef __attribute__((ext_vector_type(4))) float f32x4;
typedef __attribute__((ext_vector_type(4))) unsigned short u16x4;

__device__ __forceinline__ unsigned short f2bf(float f) {
  unsigned int u = __builtin_bit_cast(unsigned int, f);
  u += 0x7fffu + ((u >> 16) & 1u);
  return (unsigned short)(u >> 16);
}
__device__ __forceinline__ float bf2f(unsigned short h) {
  return __builtin_bit_cast(float, ((unsigned int)h) << 16);
}

// Repack Wq (512x512), Wk (512x768), Wv (512x768) f32 -> bf16 fragments in
// MFMA operand order: frag[head][kk32][n][lane][8 shorts] -> B-fragment load
// is lane*16B contiguous: one coalesced 1KB wave load.
__global__ void cvt_weights(const float* __restrict__ wq,
                            const float* __restrict__ wk,
                            const float* __restrict__ wv,
                            unsigned short* __restrict__ o) {
  int stride = gridDim.x * blockDim.x;
  int i0 = blockIdx.x * blockDim.x + threadIdx.x;
  for (int t = i0; t < 32768; t += stride) {
    int lane = t & 63, n = (t >> 6) & 3, kk32 = (t >> 8) & 15, head = t >> 12;
    int row = head * 64 + n * 16 + (lane & 15);
    int k   = kk32 * 32 + (lane >> 4) * 8;
    const float* s = wq + (size_t)row * 512 + k;
    unsigned short* d = o + (size_t)t * 8;
    #pragma unroll
    for (int e = 0; e < 8; ++e) d[e] = f2bf(s[e]);
  }
  for (int t = i0; t < 49152; t += stride) {
    int lane = t & 63, n = (t >> 6) & 3, rem = t >> 8;
    int kk32 = rem % 24, head = rem / 24;
    int row = head * 64 + n * 16 + (lane & 15);
    int k   = kk32 * 32 + (lane >> 4) * 8;
    const float* s = wk + (size_t)row * 768 + k;
    unsigned short* d = o + 262144 + (size_t)t * 8;
    #pragma unroll
    for (int e = 0; e < 8; ++e) d[e] = f2bf(s[e]);
  }
  for (int t = i0; t < 49152; t += stride) {
    int lane = t & 63, n = (t >> 6) & 3, rem = t >> 8;
    int kk32 = rem % 24, head = rem / 24;
    int row = head * 64 + n * 16 + (lane & 15);
    int k   = kk32 * 32 + (lane >> 4) * 8;
    const float* s = wv + (size_t)row * 768 + k;
    unsigned short* d = o + 655360 + (size_t)t * 8;
    #pragma unroll
    for (int e = 0; e < 8; ++e) d[e] = f2bf(s[e]);
  }
}

// Persistent: grid 256 x 1024 threads (16 waves = 4/SIMD), 2 tiles of 64 rows.
// Wave PAIR per head: head = wid>>1, half = wid&1, each wave owns 2 n-tiles
// (32 of the head's 64 channels) -> per-wave acc = 4x2 f32x4 = 32 regs, so all
// phases fit the 128-reg cap of 4 waves/SIMD. Gate dot is completed with one
// cross-pair LDS reduce. 3 barriers/tile; y2 stores drain under next tile.
__global__ __launch_bounds__(NT, 4)
void fused_xattn(const float* __restrict__ x, const float* __restrict__ xf,
                 const float* __restrict__ nw, const float* __restrict__ nb,
                 const float* __restrict__ tw, const float* __restrict__ tb,
                 const unsigned short* __restrict__ wbf,
                 float* __restrict__ out) {
  __shared__ __attribute__((aligned(16))) char ldsF[98304];  // [64][768] bf16 swz
  __shared__ __attribute__((aligned(16))) char ldsX[65536];  // [64][512] bf16 swz + gate scratch
  const int tid   = threadIdx.x;
  const int lane  = tid & 63;
  const int wid   = tid >> 6;          // 0..15
  const int head  = wid >> 1;
  const int half  = wid & 1;           // which 2 n-tiles of the head
  const int lr    = lane & 15;
  const int lkb   = (lane >> 4) * 8;
  const int lrow4 = (lane >> 4) * 4;

  float* __restrict__ y1 = out;
  float* __restrict__ y2 = out + 16777216L;

  const unsigned short* bq = wbf +          (size_t)head * 32768 + half * 1024 + lane * 8;
  const unsigned short* bk = wbf + 262144 + (size_t)head * 49152 + half * 1024 + lane * 8;
  const unsigned short* bv = wbf + 655360 + (size_t)head * 49152 + half * 1024 + lane * 8;

  for (int t = 0; t < 2; ++t) {
    const long row0 = (long)blockIdx.x * 128 + t * 64;

    // ---- Phase X: load 4 x-rows, LN (f32 stats), -> ldsX --------------------
    {
      f32x4 t0[4], t1[4];
      #pragma unroll
      for (int j = 0; j < 4; ++j) {
        const f32x4* rp = (const f32x4*)(x + (row0 + wid * 4 + j) * 512);
        t0[j] = rp[lane]; t1[j] = rp[lane + 64];
      }
      const f32x4* g4 = (const f32x4*)nw;
      const f32x4* b4 = (const f32x4*)nb;
      f32x4 g0 = g4[lane], g1 = g4[lane + 64];
      f32x4 c0 = b4[lane], c1 = b4[lane + 64];
      #pragma unroll
      for (int j = 0; j < 4; ++j) {
        f32x4 a = t0[j], b = t1[j];
        float s  = a.x + a.y + a.z + a.w + b.x + b.y + b.z + b.w;
        float s2 = a.x*a.x + a.y*a.y + a.z*a.z + a.w*a.w
                 + b.x*b.x + b.y*b.y + b.z*b.z + b.w*b.w;
        #pragma unroll
        for (int m = 1; m < 64; m <<= 1) { s += __shfl_xor(s, m, 64); s2 += __shfl_xor(s2, m, 64); }
        float mean = s * (1.0f / 512.0f);
        float var  = s2 * (1.0f / 512.0f) - mean * mean;
        float rs   = rsqrtf(var + 1e-5f);
        u16x4 o0 = { f2bf((a.x - mean) * rs * g0.x + c0.x),
                     f2bf((a.y - mean) * rs * g0.y + c0.y),
                     f2bf((a.z - mean) * rs * g0.z + c0.z),
                     f2bf((a.w - mean) * rs * g0.w + c0.w) };
        u16x4 o1 = { f2bf((b.x - mean) * rs * g1.x + c1.x),
                     f2bf((b.y - mean) * rs * g1.y + c1.y),
                     f2bf((b.z - mean) * rs * g1.z + c1.z),
                     f2bf((b.w - mean) * rs * g1.w + c1.w) };
        int r = wid * 4 + j;
        int base = r * 1024, sw = (r & 7) << 4;
        *(u16x4*)(ldsX + ((base +       lane * 8) ^ sw)) = o0;
        *(u16x4*)(ldsX + ((base + 512 + lane * 8) ^ sw)) = o1;
      }
    }
    __syncthreads();   // B1: ldsX ready (also: everyone done with prev ldsF)

    // ---- issue xf loads: rows 0,1 packed to raw bf16; rows 2,3 held f32 ----
    u16x4 fA[2][3];
    f32x4 fB[2][3];
    {
      f32x4 a0, a1, a2, b0, b1, b2;
      {
        const f32x4* rp = (const f32x4*)(xf + (row0 + wid * 4 + 0) * 768);
        a0 = rp[lane]; a1 = rp[lane + 64]; a2 = rp[lane + 128];
      }
      {
        const f32x4* rp = (const f32x4*)(xf + (row0 + wid * 4 + 1) * 768);
        b0 = rp[lane]; b1 = rp[lane + 64]; b2 = rp[lane + 128];
      }
      #pragma unroll
      for (int jj = 0; jj < 2; ++jj) {
        const f32x4* rp = (const f32x4*)(xf + (row0 + wid * 4 + 2 + jj) * 768);
        fB[jj][0] = rp[lane]; fB[jj][1] = rp[lane + 64]; fB[jj][2] = rp[lane + 128];
      }
      fA[0][0] = u16x4{ f2bf(a0.x), f2bf(a0.y), f2bf(a0.z), f2bf(a0.w) };
      fA[0][1] = u16x4{ f2bf(a1.x), f2bf(a1.y), f2bf(a1.z), f2bf(a1.w) };
      fA[0][2] = u16x4{ f2bf(a2.x), f2bf(a2.y), f2bf(a2.z), f2bf(a2.w) };
      fA[1][0] = u16x4{ f2bf(b0.x), f2bf(b0.y), f2bf(b0.z), f2bf(b0.w) };
      fA[1][1] = u16x4{ f2bf(b1.x), f2bf(b1.y), f2bf(b1.z), f2bf(b1.w) };
      fA[1][2] = u16x4{ f2bf(b2.x), f2bf(b2.y), f2bf(b2.z), f2bf(b2.w) };
    }

    // ---- q GEMM: K=512 from ldsX, 1-deep B prefetch, A in-loop -------------
    f32x4 qa[4][2] = {};
    {
      short8 bc[2];
      #pragma unroll
      for (int n = 0; n < 2; ++n) bc[n] = *(const short8*)(bq + n * 512);
      #pragma unroll
      for (int kk = 0; kk < 16; ++kk) {
        short8 a[4];
        #pragma unroll
        for (int m = 0; m < 4; ++m) {
          int row = m * 16 + lr;
          a[m] = *(const short8*)(ldsX + ((row * 1024 + (kk * 32 + lkb) * 2) ^ ((row & 7) << 4)));
        }
        short8 bn[2];
        if (kk < 15) {
          #pragma unroll
          for (int n = 0; n < 2; ++n)
            bn[n] = *(const short8*)(bq + (kk + 1) * 2048 + n * 512);
        }
        #pragma unroll
        for (int n = 0; n < 2; ++n)
          #pragma unroll
          for (int m = 0; m < 4; ++m)
            qa[m][n] = __builtin_amdgcn_mfma_f32_16x16x32_bf16(a[m], bc[n], qa[m][n], 0, 0, 0);
        if (kk < 15) { bc[0] = bn[0]; bc[1] = bn[1]; }
      }
    }

    // ---- LN(xf) -> ldsF (rows 0,1 from bf16; rows 2,3 from f32) ------------
    {
      const f32x4* g4 = (const f32x4*)tw;
      const f32x4* b4 = (const f32x4*)tb;
      f32x4 g0 = g4[lane], g1 = g4[lane + 64], g2 = g4[lane + 128];
      f32x4 c0 = b4[lane], c1 = b4[lane + 64], c2 = b4[lane + 128];
      #pragma unroll
      for (int j = 0; j < 4; ++j) {
        f32x4 a, b, c;
        if (j < 2) {
          a = f32x4{ bf2f(fA[j][0].x), bf2f(fA[j][0].y), bf2f(fA[j][0].z), bf2f(fA[j][0].w) };
          b = f32x4{ bf2f(fA[j][1].x), bf2f(fA[j][1].y), bf2f(fA[j][1].z), bf2f(fA[j][1].w) };
          c = f32x4{ bf2f(fA[j][2].x), bf2f(fA[j][2].y), bf2f(fA[j][2].z), bf2f(fA[j][2].w) };
        } else {
          a = fB[j - 2][0]; b = fB[j - 2][1]; c = fB[j - 2][2];
        }
        float s  = a.x + a.y + a.z + a.w + b.x + b.y + b.z + b.w
                 + c.x + c.y + c.z + c.w;
        float s2 = a.x*a.x + a.y*a.y + a.z*a.z + a.w*a.w
                 + b.x*b.x + b.y*b.y + b.z*b.z + b.w*b.w
                 + c.x*c.x + c.y*c.y + c.z*c.z + c.w*c.w;
        #pragma unroll
        for (int m = 1; m < 64; m <<= 1) { s += __shfl_xor(s, m, 64); s2 += __shfl_xor(s2, m, 64); }
        float mean = s * (1.0f / 768.0f);
        float var  = s2 * (1.0f / 768.0f) - mean * mean;
        float rs   = rsqrtf(var + 1e-5f);
        u16x4 o0 = { f2bf((a.x - mean) * rs * g0.x + c0.x),
                     f2bf((a.y - mean) * rs * g0.y + c0.y),
                     f2bf((a.z - mean) * rs * g0.z + c0.z),
                     f2bf((a.w - mean) * rs * g0.w + c0.w) };
        u16x4 o1 = { f2bf((b.x - mean) * rs * g1.x + c1.x),
                     f2bf((b.y - mean) * rs * g1.y + c1.y),
                     f2bf((b.z - mean) * rs * g1.z + c1.z),
                     f2bf((b.w - mean) * rs * g1.w + c1.w) };
        u16x4 o2 = { f2bf((c.x - mean) * rs * g2.x + c2.x),
                     f2bf((c.y - mean) * rs * g2.y + c2.y),
                     f2bf((c.z - mean) * rs * g2.z + c2.z),
                     f2bf((c.w - mean) * rs * g2.w + c2.w) };
        int r = wid * 4 + j;
        int base = r * 1536, sw = (r & 7) << 4;
        *(u16x4*)(ldsF + ((base +        lane * 8) ^ sw)) = o0;
        *(u16x4*)(ldsF + ((base + 512  + lane * 8) ^ sw)) = o1;
        *(u16x4*)(ldsF + ((base + 1024 + lane * 8) ^ sw)) = o2;
      }
    }
    __syncthreads();   // B2: ldsF ready

    // ---- k GEMM: K=768 from ldsF ------------------------------------------
    f32x4 ka[4][2] = {};
    {
      short8 bc[2];
      #pragma unroll
      for (int n = 0; n < 2; ++n) bc[n] = *(const short8*)(bk + n * 512);
      #pragma unroll
      for (int kk = 0; kk < 24; ++kk) {
        short8 a[4];
        #pragma unroll
        for (int m = 0; m < 4; ++m) {
          int row = m * 16 + lr;
          a[m] = *(const short8*)(ldsF + ((row * 1536 + (kk * 32 + lkb) * 2) ^ ((row & 7) << 4)));
        }
        short8 bn[2];
        if (kk < 23) {
          #pragma unroll
          for (int n = 0; n < 2; ++n)
            bn[n] = *(const short8*)(bk + (kk + 1) * 2048 + n * 512);
        }
        #pragma unroll
        for (int n = 0; n < 2; ++n)
          #pragma unroll
          for (int m = 0; m < 4; ++m)
            ka[m][n] = __builtin_amdgcn_mfma_f32_16x16x32_bf16(a[m], bc[n], ka[m][n], 0, 0, 0);
        if (kk < 23) { bc[0] = bn[0]; bc[1] = bn[1]; }
      }
    }

    // ---- gate: partial (2 n-tiles + 16 lanes), cross-pair reduce via LDS ---
    float wgt[4][4];
    float* scr = (float*)ldsX;   // ldsX data fully consumed by q GEMM
    #pragma unroll
    for (int m = 0; m < 4; ++m) {
      #pragma unroll
      for (int r = 0; r < 4; ++r) {
        float p = qa[m][0][r] * ka[m][0][r] + qa[m][1][r] * ka[m][1][r];
        #pragma unroll
        for (int msk = 1; msk < 16; msk <<= 1) p += __shfl_xor(p, msk, 64);
        wgt[m][r] = p;
        if ((lane & 15) == 0)
          scr[((wid * 4 + (lane >> 4)) * 4 + m) * 4 + r] = p;
      }
    }
    __syncthreads();   // B3: gate scratch ready
    #pragma unroll
    for (int m = 0; m < 4; ++m)
      #pragma unroll
      for (int r = 0; r < 4; ++r)
        wgt[m][r] = (wgt[m][r] + scr[(((wid ^ 1) * 4 + (lane >> 4)) * 4 + m) * 4 + r]) * 0.125f;

    // ---- y1 = (1-w)*q (frees qa) -------------------------------------------
    #pragma unroll
    for (int m = 0; m < 4; ++m) {
      #pragma unroll
      for (int r = 0; r < 4; ++r) {
        float f = 1.0f - wgt[m][r];
        long grow = row0 + m * 16 + lrow4 + r;
        #pragma unroll
        for (int n = 0; n < 2; ++n) {
          int ch = head * 64 + (half * 2 + n) * 16 + lr;
          y1[grow * 512 + ch] = f * qa[m][n][r];
        }
      }
    }

    // ---- v GEMM: K=768 from ldsF, then y2 = w*v ----------------------------
    f32x4 va[4][2] = {};
    {
      short8 bc[2];
      #pragma unroll
      for (int n = 0; n < 2; ++n) bc[n] = *(const short8*)(bv + n * 512);
      #pragma unroll
      for (int kk = 0; kk < 24; ++kk) {
        short8 a[4];
        #pragma unroll
        for (int m = 0; m < 4; ++m) {
          int row = m * 16 + lr;
          a[m] = *(const short8*)(ldsF + ((row * 1536 + (kk * 32 + lkb) * 2) ^ ((row & 7) << 4)));
        }
        short8 bn[2];
        if (kk < 23) {
          #pragma unroll
          for (int n = 0; n < 2; ++n)
            bn[n] = *(const short8*)(bv + (kk + 1) * 2048 + n * 512);
        }
        #pragma unroll
        for (int n = 0; n < 2; ++n)
          #pragma unroll
          for (int m = 0; m < 4; ++m)
            va[m][n] = __builtin_amdgcn_mfma_f32_16x16x32_bf16(a[m], bc[n], va[m][n], 0, 0, 0);
        if (kk < 23) { bc[0] = bn[0]; bc[1] = bn[1]; }
      }
    }
    #pragma unroll
    for (int m = 0; m < 4; ++m) {
      #pragma unroll
      for (int r = 0; r < 4; ++r) {
        float f = wgt[m][r];
        long grow = row0 + m * 16 + lrow4 + r;
        #pragma unroll
        for (int n = 0; n < 2; ++n) {
          int ch = head * 64 + (half * 2 + n) * 16 + lr;
          y2[grow * 512 + ch] = f * va[m][n][r];
        }
      }
    }
    // no barrier: next tile's B1 provides the needed ordering for ldsF/ldsX
  }
}

extern "C" void kernel_launch(void* const* d_in, const int* in_sizes, int n_in,
                              void* d_out, int out_size, void* d_ws, size_t ws_size,
                              hipStream_t stream) {
  const float* x  = (const float*)d_in[0];
  const float* xf = (const float*)d_in[1];
  const float* nw = (const float*)d_in[2];
  const float* nb = (const float*)d_in[3];
  const float* tw = (const float*)d_in[4];
  const float* tb = (const float*)d_in[5];
  const float* wq = (const float*)d_in[6];
  const float* wk = (const float*)d_in[7];
  const float* wv = (const float*)d_in[8];
  unsigned short* wbf = (unsigned short*)d_ws;   // 2 MB bf16 packed weights

  cvt_weights<<<256, 256, 0, stream>>>(wq, wk, wv, wbf);
  fused_xattn<<<256, NT, 0, stream>>>(x, xf, nw, nb, tw, tb, wbf, (float*)d_out);
}

// Round 9
// 182.887 us; speedup vs baseline: 4.2311x; 4.2311x over previous
//
#include <hip/hip_runtime.h>

#define NT 512
#define MT 32   // rows per block; LDS 80KB -> 2 blocks/CU co-resident

typedef __attribute__((ext_vector_type(8))) short short8;
typedef __attribute__((ext_vector_type(4))) float f32x4;
typedef __attribute__((ext_vector_type(4))) unsigned short u16x4;

__device__ __forceinline__ unsigned short f2bf(float f) {
  unsigned int u = __builtin_bit_cast(unsigned int, f);
  u += 0x7fffu + ((u >> 16) & 1u);
  return (unsigned short)(u >> 16);
}

// Repack Wq (512x512), Wk (512x768), Wv (512x768) f32 -> bf16 fragments in
// MFMA operand order: frag[head][kk32][n][lane][8 shorts] -> B-fragment load
// is lane*16B contiguous: one coalesced 1KB wave load.
__global__ void cvt_weights(const float* __restrict__ wq,
                            const float* __restrict__ wk,
                            const float* __restrict__ wv,
                            unsigned short* __restrict__ o) {
  int stride = gridDim.x * blockDim.x;
  int i0 = blockIdx.x * blockDim.x + threadIdx.x;
  for (int t = i0; t < 32768; t += stride) {
    int lane = t & 63, n = (t >> 6) & 3, kk32 = (t >> 8) & 15, head = t >> 12;
    int row = head * 64 + n * 16 + (lane & 15);
    int k   = kk32 * 32 + (lane >> 4) * 8;
    const float* s = wq + (size_t)row * 512 + k;
    unsigned short* d = o + (size_t)t * 8;
    #pragma unroll
    for (int e = 0; e < 8; ++e) d[e] = f2bf(s[e]);
  }
  for (int t = i0; t < 49152; t += stride) {
    int lane = t & 63, n = (t >> 6) & 3, rem = t >> 8;
    int kk32 = rem % 24, head = rem / 24;
    int row = head * 64 + n * 16 + (lane & 15);
    int k   = kk32 * 32 + (lane >> 4) * 8;
    const float* s = wk + (size_t)row * 768 + k;
    unsigned short* d = o + 262144 + (size_t)t * 8;
    #pragma unroll
    for (int e = 0; e < 8; ++e) d[e] = f2bf(s[e]);
  }
  for (int t = i0; t < 49152; t += stride) {
    int lane = t & 63, n = (t >> 6) & 3, rem = t >> 8;
    int kk32 = rem % 24, head = rem / 24;
    int row = head * 64 + n * 16 + (lane & 15);
    int k   = kk32 * 32 + (lane >> 4) * 8;
    const float* s = wv + (size_t)row * 768 + k;
    unsigned short* d = o + 655360 + (size_t)t * 8;
    #pragma unroll
    for (int e = 0; e < 8; ++e) d[e] = f2bf(s[e]);
  }
}

// 32 rows/block, 8 waves (wave == head), 2 blocks/CU (launch_bounds 2nd arg
// observed to act as min BLOCKS/CU: (512,2) -> 16 waves/CU -> 128-reg cap).
// Phase order k->q->v caps live accumulators at qa+ka = 64 regs.
// LDS: bufA = xf tile [32][768] bf16 (48KB, lives through v GEMM),
//      bufB = x  tile [32][512] bf16 (32KB). Two barriers total.
__global__ __launch_bounds__(NT, 2)
void fused_xattn(const float* __restrict__ x, const float* __restrict__ xf,
                 const float* __restrict__ nw, const float* __restrict__ nb,
                 const float* __restrict__ tw, const float* __restrict__ tb,
                 const unsigned short* __restrict__ wbf,
                 float* __restrict__ out) {
  __shared__ __attribute__((aligned(16))) char smem[81920];  // A:0..48K, B:48K..80K
  char* bufA = smem;
  char* bufB = smem + 49152;
  const int tid   = threadIdx.x;
  const int lane  = tid & 63;
  const int wid   = tid >> 6;          // wave == head
  const int lr    = lane & 15;
  const int lkb   = (lane >> 4) * 8;
  const int lrow4 = (lane >> 4) * 4;

  const long row0 = (long)blockIdx.x * MT;
  float* __restrict__ y1 = out;
  float* __restrict__ y2 = out + 16777216L;

  // ---- stage LN(xf): batch-issue 12 loads (4 rows x 3 seg), LN, -> bufA -----
  {
    f32x4 t0[4], t1[4], t2[4];
    #pragma unroll
    for (int j = 0; j < 4; ++j) {
      const f32x4* rp = (const f32x4*)(xf + (row0 + wid * 4 + j) * 768);
      t0[j] = rp[lane]; t1[j] = rp[lane + 64]; t2[j] = rp[lane + 128];
    }
    const f32x4* g4 = (const f32x4*)tw;
    const f32x4* b4 = (const f32x4*)tb;
    f32x4 g0 = g4[lane], g1 = g4[lane + 64], g2 = g4[lane + 128];
    f32x4 c0 = b4[lane], c1 = b4[lane + 64], c2 = b4[lane + 128];
    #pragma unroll
    for (int j = 0; j < 4; ++j) {
      f32x4 a = t0[j], b = t1[j], c = t2[j];
      float s  = a.x + a.y + a.z + a.w + b.x + b.y + b.z + b.w
               + c.x + c.y + c.z + c.w;
      float s2 = a.x*a.x + a.y*a.y + a.z*a.z + a.w*a.w
               + b.x*b.x + b.y*b.y + b.z*b.z + b.w*b.w
               + c.x*c.x + c.y*c.y + c.z*c.z + c.w*c.w;
      #pragma unroll
      for (int m = 1; m < 64; m <<= 1) { s += __shfl_xor(s, m, 64); s2 += __shfl_xor(s2, m, 64); }
      float mean = s * (1.0f / 768.0f);
      float var  = s2 * (1.0f / 768.0f) - mean * mean;
      float rs   = rsqrtf(var + 1e-5f);
      u16x4 o0 = { f2bf((a.x - mean) * rs * g0.x + c0.x),
                   f2bf((a.y - mean) * rs * g0.y + c0.y),
                   f2bf((a.z - mean) * rs * g0.z + c0.z),
                   f2bf((a.w - mean) * rs * g0.w + c0.w) };
      u16x4 o1 = { f2bf((b.x - mean) * rs * g1.x + c1.x),
                   f2bf((b.y - mean) * rs * g1.y + c1.y),
                   f2bf((b.z - mean) * rs * g1.z + c1.z),
                   f2bf((b.w - mean) * rs * g1.w + c1.w) };
      u16x4 o2 = { f2bf((c.x - mean) * rs * g2.x + c2.x),
                   f2bf((c.y - mean) * rs * g2.y + c2.y),
                   f2bf((c.z - mean) * rs * g2.z + c2.z),
                   f2bf((c.w - mean) * rs * g2.w + c2.w) };
      int r = wid * 4 + j;
      int base = r * 1536, sw = (r & 7) << 4;
      *(u16x4*)(bufA + ((base +        lane * 8) ^ sw)) = o0;
      *(u16x4*)(bufA + ((base + 512  + lane * 8) ^ sw)) = o1;
      *(u16x4*)(bufA + ((base + 1024 + lane * 8) ^ sw)) = o2;
    }
  }

  // ---- issue x loads now; consumed after k GEMM (latency hidden) ------------
  f32x4 xr0[4], xr1[4];
  #pragma unroll
  for (int j = 0; j < 4; ++j) {
    const f32x4* rp = (const f32x4*)(x + (row0 + wid * 4 + j) * 512);
    xr0[j] = rp[lane]; xr1[j] = rp[lane + 64];
  }
  __syncthreads();   // bufA ready

  // ---- k GEMM: K=768 from bufA, 1-deep B prefetch, A inline -----------------
  f32x4 ka[2][4] = {};
  {
    const unsigned short* bk = wbf + 262144 + wid * 49152 + lane * 8;
    short8 bc[4];
    #pragma unroll
    for (int n = 0; n < 4; ++n) bc[n] = *(const short8*)(bk + n * 512);
    for (int kk = 0; kk < 24; ++kk) {
      short8 a[2];
      #pragma unroll
      for (int m = 0; m < 2; ++m) {
        int row = m * 16 + lr;
        a[m] = *(const short8*)(bufA + ((row * 1536 + (kk * 32 + lkb) * 2) ^ ((row & 7) << 4)));
      }
      short8 bn[4];
      if (kk < 23) {
        #pragma unroll
        for (int n = 0; n < 4; ++n)
          bn[n] = *(const short8*)(bk + (kk + 1) * 2048 + n * 512);
      }
      #pragma unroll
      for (int n = 0; n < 4; ++n)
        #pragma unroll
        for (int m = 0; m < 2; ++m)
          ka[m][n] = __builtin_amdgcn_mfma_f32_16x16x32_bf16(a[m], bc[n], ka[m][n], 0, 0, 0);
      if (kk < 23) {
        #pragma unroll
        for (int n = 0; n < 4; ++n) bc[n] = bn[n];
      }
    }
  }

  // ---- LN(x) from regs -> bufB ----------------------------------------------
  {
    const f32x4* g4 = (const f32x4*)nw;
    const f32x4* b4 = (const f32x4*)nb;
    f32x4 g0 = g4[lane], g1 = g4[lane + 64];
    f32x4 c0 = b4[lane], c1 = b4[lane + 64];
    #pragma unroll
    for (int j = 0; j < 4; ++j) {
      f32x4 a = xr0[j], b = xr1[j];
      float s  = a.x + a.y + a.z + a.w + b.x + b.y + b.z + b.w;
      float s2 = a.x*a.x + a.y*a.y + a.z*a.z + a.w*a.w
               + b.x*b.x + b.y*b.y + b.z*b.z + b.w*b.w;
      #pragma unroll
      for (int m = 1; m < 64; m <<= 1) { s += __shfl_xor(s, m, 64); s2 += __shfl_xor(s2, m, 64); }
      float mean = s * (1.0f / 512.0f);
      float var  = s2 * (1.0f / 512.0f) - mean * mean;
      float rs   = rsqrtf(var + 1e-5f);
      u16x4 o0 = { f2bf((a.x - mean) * rs * g0.x + c0.x),
                   f2bf((a.y - mean) * rs * g0.y + c0.y),
                   f2bf((a.z - mean) * rs * g0.z + c0.z),
                   f2bf((a.w - mean) * rs * g0.w + c0.w) };
      u16x4 o1 = { f2bf((b.x - mean) * rs * g1.x + c1.x),
                   f2bf((b.y - mean) * rs * g1.y + c1.y),
                   f2bf((b.z - mean) * rs * g1.z + c1.z),
                   f2bf((b.w - mean) * rs * g1.w + c1.w) };
      int r = wid * 4 + j;
      int base = r * 1024, sw = (r & 7) << 4;
      *(u16x4*)(bufB + ((base +       lane * 8) ^ sw)) = o0;
      *(u16x4*)(bufB + ((base + 512 + lane * 8) ^ sw)) = o1;
    }
  }
  __syncthreads();   // bufB ready

  // ---- q GEMM: K=512 from bufB (ka stays live), 1-deep B prefetch -----------
  f32x4 qa[2][4] = {};
  {
    const unsigned short* bq = wbf + wid * 32768 + lane * 8;
    short8 bc[4];
    #pragma unroll
    for (int n = 0; n < 4; ++n) bc[n] = *(const short8*)(bq + n * 512);
    for (int kk = 0; kk < 16; ++kk) {
      short8 a[2];
      #pragma unroll
      for (int m = 0; m < 2; ++m) {
        int row = m * 16 + lr;
        a[m] = *(const short8*)(bufB + ((row * 1024 + (kk * 32 + lkb) * 2) ^ ((row & 7) << 4)));
      }
      short8 bn[4];
      if (kk < 15) {
        #pragma unroll
        for (int n = 0; n < 4; ++n)
          bn[n] = *(const short8*)(bq + (kk + 1) * 2048 + n * 512);
      }
      #pragma unroll
      for (int n = 0; n < 4; ++n)
        #pragma unroll
        for (int m = 0; m < 2; ++m)
          qa[m][n] = __builtin_amdgcn_mfma_f32_16x16x32_bf16(a[m], bc[n], qa[m][n], 0, 0, 0);
      if (kk < 15) {
        #pragma unroll
        for (int n = 0; n < 4; ++n) bc[n] = bn[n];
      }
    }
  }

  // ---- gate + y1 = (1-w)*q (frees qa, ka) -----------------------------------
  float wgt[2][4];
  #pragma unroll
  for (int m = 0; m < 2; ++m) {
    #pragma unroll
    for (int r = 0; r < 4; ++r) {
      float p = 0.0f;
      #pragma unroll
      for (int n = 0; n < 4; ++n) p += qa[m][n][r] * ka[m][n][r];
      #pragma unroll
      for (int msk = 1; msk < 16; msk <<= 1) p += __shfl_xor(p, msk, 64);
      wgt[m][r] = p * 0.125f;   // 1/sqrt(64)
    }
  }
  #pragma unroll
  for (int m = 0; m < 2; ++m) {
    #pragma unroll
    for (int r = 0; r < 4; ++r) {
      float f = 1.0f - wgt[m][r];
      long grow = row0 + m * 16 + lrow4 + r;
      #pragma unroll
      for (int n = 0; n < 4; ++n) {
        int ch = wid * 64 + n * 16 + lr;
        y1[grow * 512 + ch] = f * qa[m][n][r];
      }
    }
  }

  // ---- v GEMM: K=768 from bufA (still resident), then y2 = w*v --------------
  f32x4 va[2][4] = {};
  {
    const unsigned short* bv = wbf + 655360 + wid * 49152 + lane * 8;
    short8 bc[4];
    #pragma unroll
    for (int n = 0; n < 4; ++n) bc[n] = *(const short8*)(bv + n * 512);
    for (int kk = 0; kk < 24; ++kk) {
      short8 a[2];
      #pragma unroll
      for (int m = 0; m < 2; ++m) {
        int row = m * 16 + lr;
        a[m] = *(const short8*)(bufA + ((row * 1536 + (kk * 32 + lkb) * 2) ^ ((row & 7) << 4)));
      }
      short8 bn[4];
      if (kk < 23) {
        #pragma unroll
        for (int n = 0; n < 4; ++n)
          bn[n] = *(const short8*)(bv + (kk + 1) * 2048 + n * 512);
      }
      #pragma unroll
      for (int n = 0; n < 4; ++n)
        #pragma unroll
        for (int m = 0; m < 2; ++m)
          va[m][n] = __builtin_amdgcn_mfma_f32_16x16x32_bf16(a[m], bc[n], va[m][n], 0, 0, 0);
      if (kk < 23) {
        #pragma unroll
        for (int n = 0; n < 4; ++n) bc[n] = bn[n];
      }
    }
  }
  #pragma unroll
  for (int m = 0; m < 2; ++m) {
    #pragma unroll
    for (int r = 0; r < 4; ++r) {
      float f = wgt[m][r];
      long grow = row0 + m * 16 + lrow4 + r;
      #pragma unroll
      for (int n = 0; n < 4; ++n) {
        int ch = wid * 64 + n * 16 + lr;
        y2[grow * 512 + ch] = f * va[m][n][r];
      }
    }
  }
}

extern "C" void kernel_launch(void* const* d_in, const int* in_sizes, int n_in,
                              void* d_out, int out_size, void* d_ws, size_t ws_size,
                              hipStream_t stream) {
  const float* x  = (const float*)d_in[0];
  const float* xf = (const float*)d_in[1];
  const float* nw = (const float*)d_in[2];
  const float* nb = (const float*)d_in[3];
  const float* tw = (const float*)d_in[4];
  const float* tb = (const float*)d_in[5];
  const float* wq = (const float*)d_in[6];
  const float* wk = (const float*)d_in[7];
  const float* wv = (const float*)d_in[8];
  unsigned short* wbf = (unsigned short*)d_ws;   // 2 MB bf16 packed weights

  cvt_weights<<<256, 256, 0, stream>>>(wq, wk, wv, wbf);
  fused_xattn<<<1024, NT, 0, stream>>>(x, xf, nw, nb, tw, tb, wbf, (float*)d_out);
}

// Round 10
// 128.927 us; speedup vs baseline: 6.0019x; 1.4185x over previous
//
#include <hip/hip_runtime.h>

#define NT 512
#define MT 64   // rows per block, 1 block/CU (LDS 160KB), 8 waves, wave == head

typedef __attribute__((ext_vector_type(8))) short short8;
typedef __attribute__((ext_vector_type(4))) float f32x4;
typedef __attribute__((ext_vector_type(4))) unsigned short u16x4;

__device__ __forceinline__ unsigned short f2bf(float f) {
  unsigned int u = __builtin_bit_cast(unsigned int, f);
  u += 0x7fffu + ((u >> 16) & 1u);
  return (unsigned short)(u >> 16);
}

// Repack Wq (512x512), Wk (512x768), Wv (512x768) f32 -> bf16 fragments in
// MFMA operand order: frag[head][kk32][n][lane][8 shorts] -> B-fragment load
// is lane*16B contiguous: one coalesced 1KB wave load.
__global__ void cvt_weights(const float* __restrict__ wq,
                            const float* __restrict__ wk,
                            const float* __restrict__ wv,
                            unsigned short* __restrict__ o) {
  int stride = gridDim.x * blockDim.x;
  int i0 = blockIdx.x * blockDim.x + threadIdx.x;
  for (int t = i0; t < 32768; t += stride) {
    int lane = t & 63, n = (t >> 6) & 3, kk32 = (t >> 8) & 15, head = t >> 12;
    int row = head * 64 + n * 16 + (lane & 15);
    int k   = kk32 * 32 + (lane >> 4) * 8;
    const float* s = wq + (size_t)row * 512 + k;
    unsigned short* d = o + (size_t)t * 8;
    #pragma unroll
    for (int e = 0; e < 8; ++e) d[e] = f2bf(s[e]);
  }
  for (int t = i0; t < 49152; t += stride) {
    int lane = t & 63, n = (t >> 6) & 3, rem = t >> 8;
    int kk32 = rem % 24, head = rem / 24;
    int row = head * 64 + n * 16 + (lane & 15);
    int k   = kk32 * 32 + (lane >> 4) * 8;
    const float* s = wk + (size_t)row * 768 + k;
    unsigned short* d = o + 262144 + (size_t)t * 8;
    #pragma unroll
    for (int e = 0; e < 8; ++e) d[e] = f2bf(s[e]);
  }
  for (int t = i0; t < 49152; t += stride) {
    int lane = t & 63, n = (t >> 6) & 3, rem = t >> 8;
    int kk32 = rem % 24, head = rem / 24;
    int row = head * 64 + n * 16 + (lane & 15);
    int k   = kk32 * 32 + (lane >> 4) * 8;
    const float* s = wv + (size_t)row * 768 + k;
    unsigned short* d = o + 655360 + (size_t)t * 8;
    #pragma unroll
    for (int e = 0; e < 8; ++e) d[e] = f2bf(s[e]);
  }
}

// Register model (measured): wave slots/SIMD = floor(512/(VGPR+AGPR)).
// Accumulator peak qa+ka = 128 AGPR pins us at 2 waves/SIMD; so staging is
// CHUNKED (<=50 transient VGPR) and the freed regs buy 2-deep B prefetch.
__global__ __launch_bounds__(NT, 2)
void fused_xattn(const float* __restrict__ x, const float* __restrict__ xf,
                 const float* __restrict__ nw, const float* __restrict__ nb,
                 const float* __restrict__ tw, const float* __restrict__ tb,
                 const unsigned short* __restrict__ wbf,
                 float* __restrict__ out) {
  __shared__ __attribute__((aligned(16))) char ldsX[65536];  // [64][512] bf16 swz
  __shared__ __attribute__((aligned(16))) char ldsF[98304];  // [64][768] bf16 swz
  const int tid   = threadIdx.x;
  const int lane  = tid & 63;
  const int wid   = tid >> 6;          // wave == head
  const int lr    = lane & 15;
  const int lkb   = (lane >> 4) * 8;
  const int lrow4 = (lane >> 4) * 4;

  const long row0 = (long)blockIdx.x * MT;
  float* __restrict__ y1 = out;
  float* __restrict__ y2 = out + 16777216L;

  // ================= S1: LN(x) -> ldsX, two 4-row chunks =====================
  {
    const f32x4* g4 = (const f32x4*)nw;
    const f32x4* b4 = (const f32x4*)nb;
    f32x4 g0 = g4[lane], g1 = g4[lane + 64];
    f32x4 c0 = b4[lane], c1 = b4[lane + 64];
    #pragma unroll
    for (int cch = 0; cch < 2; ++cch) {
      f32x4 t0[4], t1[4];
      #pragma unroll
      for (int j = 0; j < 4; ++j) {
        const f32x4* rp = (const f32x4*)(x + (row0 + wid + 8 * (cch * 4 + j)) * 512);
        t0[j] = rp[lane]; t1[j] = rp[lane + 64];
      }
      #pragma unroll
      for (int j = 0; j < 4; ++j) {
        f32x4 a = t0[j], b = t1[j];
        float s  = a.x + a.y + a.z + a.w + b.x + b.y + b.z + b.w;
        float s2 = a.x*a.x + a.y*a.y + a.z*a.z + a.w*a.w
                 + b.x*b.x + b.y*b.y + b.z*b.z + b.w*b.w;
        #pragma unroll
        for (int m = 1; m < 64; m <<= 1) { s += __shfl_xor(s, m, 64); s2 += __shfl_xor(s2, m, 64); }
        float mean = s * (1.0f / 512.0f);
        float var  = s2 * (1.0f / 512.0f) - mean * mean;
        float rs   = rsqrtf(var + 1e-5f);
        u16x4 o0 = { f2bf((a.x - mean) * rs * g0.x + c0.x),
                     f2bf((a.y - mean) * rs * g0.y + c0.y),
                     f2bf((a.z - mean) * rs * g0.z + c0.z),
                     f2bf((a.w - mean) * rs * g0.w + c0.w) };
        u16x4 o1 = { f2bf((b.x - mean) * rs * g1.x + c1.x),
                     f2bf((b.y - mean) * rs * g1.y + c1.y),
                     f2bf((b.z - mean) * rs * g1.z + c1.z),
                     f2bf((b.w - mean) * rs * g1.w + c1.w) };
        int r = wid + 8 * (cch * 4 + j);
        int base = r * 1024, sw = (r & 7) << 4;
        *(u16x4*)(ldsX + ((base +       lane * 8) ^ sw)) = o0;
        *(u16x4*)(ldsX + ((base + 512 + lane * 8) ^ sw)) = o1;
      }
    }
  }
  __syncthreads();   // B1: ldsX ready

  // ---- issue xf chunk-0 loads; latency hides under q GEMM -------------------
  f32x4 f0[4], f1[4], f2[4];
  #pragma unroll
  for (int j = 0; j < 4; ++j) {
    const f32x4* rp = (const f32x4*)(xf + (row0 + wid + 8 * j) * 768);
    f0[j] = rp[lane]; f1[j] = rp[lane + 64]; f2[j] = rp[lane + 128];
  }

  // ================= q GEMM: K=512, 2-deep B prefetch ========================
  f32x4 qa[4][4] = {};
  {
    const unsigned short* bq = wbf + wid * 32768 + lane * 8;
    short8 b0[4], b1[4];
    #pragma unroll
    for (int n = 0; n < 4; ++n) {
      b0[n] = *(const short8*)(bq + 0 * 2048 + n * 512);
      b1[n] = *(const short8*)(bq + 1 * 2048 + n * 512);
    }
    #pragma unroll
    for (int p = 0; p < 8; ++p) {
      {  // kk = 2p, consume b0, prefetch 2p+2
        short8 a[4];
        #pragma unroll
        for (int m = 0; m < 4; ++m) {
          int row = m * 16 + lr;
          a[m] = *(const short8*)(ldsX + ((row * 1024 + ((2 * p) * 32 + lkb) * 2) ^ ((row & 7) << 4)));
        }
        short8 nb[4];
        if (p < 7) {
          #pragma unroll
          for (int n = 0; n < 4; ++n) nb[n] = *(const short8*)(bq + (2 * p + 2) * 2048 + n * 512);
        }
        #pragma unroll
        for (int n = 0; n < 4; ++n)
          #pragma unroll
          for (int m = 0; m < 4; ++m)
            qa[m][n] = __builtin_amdgcn_mfma_f32_16x16x32_bf16(a[m], b0[n], qa[m][n], 0, 0, 0);
        if (p < 7) {
          #pragma unroll
          for (int n = 0; n < 4; ++n) b0[n] = nb[n];
        }
      }
      {  // kk = 2p+1, consume b1, prefetch 2p+3
        short8 a[4];
        #pragma unroll
        for (int m = 0; m < 4; ++m) {
          int row = m * 16 + lr;
          a[m] = *(const short8*)(ldsX + ((row * 1024 + ((2 * p + 1) * 32 + lkb) * 2) ^ ((row & 7) << 4)));
        }
        short8 nb[4];
        if (p < 7) {
          #pragma unroll
          for (int n = 0; n < 4; ++n) nb[n] = *(const short8*)(bq + (2 * p + 3) * 2048 + n * 512);
        }
        #pragma unroll
        for (int n = 0; n < 4; ++n)
          #pragma unroll
          for (int m = 0; m < 4; ++m)
            qa[m][n] = __builtin_amdgcn_mfma_f32_16x16x32_bf16(a[m], b1[n], qa[m][n], 0, 0, 0);
        if (p < 7) {
          #pragma unroll
          for (int n = 0; n < 4; ++n) b1[n] = nb[n];
        }
      }
    }
  }

  // ================= S2: LN(xf) -> ldsF, two 4-row chunks ====================
  {
    const f32x4* g4 = (const f32x4*)tw;
    const f32x4* b4 = (const f32x4*)tb;
    f32x4 g0 = g4[lane], g1 = g4[lane + 64], g2 = g4[lane + 128];
    f32x4 c0 = b4[lane], c1 = b4[lane + 64], c2 = b4[lane + 128];
    #pragma unroll
    for (int cch = 0; cch < 2; ++cch) {
      if (cch == 1) {   // issue chunk-1 loads, then process below
        #pragma unroll
        for (int j = 0; j < 4; ++j) {
          const f32x4* rp = (const f32x4*)(xf + (row0 + wid + 8 * (4 + j)) * 768);
          f0[j] = rp[lane]; f1[j] = rp[lane + 64]; f2[j] = rp[lane + 128];
        }
      }
      #pragma unroll
      for (int j = 0; j < 4; ++j) {
        f32x4 a = f0[j], b = f1[j], c = f2[j];
        float s  = a.x + a.y + a.z + a.w + b.x + b.y + b.z + b.w
                 + c.x + c.y + c.z + c.w;
        float s2 = a.x*a.x + a.y*a.y + a.z*a.z + a.w*a.w
                 + b.x*b.x + b.y*b.y + b.z*b.z + b.w*b.w
                 + c.x*c.x + c.y*c.y + c.z*c.z + c.w*c.w;
        #pragma unroll
        for (int m = 1; m < 64; m <<= 1) { s += __shfl_xor(s, m, 64); s2 += __shfl_xor(s2, m, 64); }
        float mean = s * (1.0f / 768.0f);
        float var  = s2 * (1.0f / 768.0f) - mean * mean;
        float rs   = rsqrtf(var + 1e-5f);
        u16x4 o0 = { f2bf((a.x - mean) * rs * g0.x + c0.x),
                     f2bf((a.y - mean) * rs * g0.y + c0.y),
                     f2bf((a.z - mean) * rs * g0.z + c0.z),
                     f2bf((a.w - mean) * rs * g0.w + c0.w) };
        u16x4 o1 = { f2bf((b.x - mean) * rs * g1.x + c1.x),
                     f2bf((b.y - mean) * rs * g1.y + c1.y),
                     f2bf((b.z - mean) * rs * g1.z + c1.z),
                     f2bf((b.w - mean) * rs * g1.w + c1.w) };
        u16x4 o2 = { f2bf((c.x - mean) * rs * g2.x + c2.x),
                     f2bf((c.y - mean) * rs * g2.y + c2.y),
                     f2bf((c.z - mean) * rs * g2.z + c2.z),
                     f2bf((c.w - mean) * rs * g2.w + c2.w) };
        int r = wid + 8 * (cch * 4 + j);
        int base = r * 1536, sw = (r & 7) << 4;
        *(u16x4*)(ldsF + ((base +        lane * 8) ^ sw)) = o0;
        *(u16x4*)(ldsF + ((base + 512  + lane * 8) ^ sw)) = o1;
        *(u16x4*)(ldsF + ((base + 1024 + lane * 8) ^ sw)) = o2;
      }
    }
  }
  __syncthreads();   // B2: ldsF ready

  // ================= k GEMM: K=768, 2-deep B prefetch (qa stays live) ========
  f32x4 ka[4][4] = {};
  {
    const unsigned short* bk = wbf + 262144 + wid * 49152 + lane * 8;
    short8 b0[4], b1[4];
    #pragma unroll
    for (int n = 0; n < 4; ++n) {
      b0[n] = *(const short8*)(bk + 0 * 2048 + n * 512);
      b1[n] = *(const short8*)(bk + 1 * 2048 + n * 512);
    }
    #pragma unroll
    for (int p = 0; p < 12; ++p) {
      {
        short8 a[4];
        #pragma unroll
        for (int m = 0; m < 4; ++m) {
          int row = m * 16 + lr;
          a[m] = *(const short8*)(ldsF + ((row * 1536 + ((2 * p) * 32 + lkb) * 2) ^ ((row & 7) << 4)));
        }
        short8 nb[4];
        if (p < 11) {
          #pragma unroll
          for (int n = 0; n < 4; ++n) nb[n] = *(const short8*)(bk + (2 * p + 2) * 2048 + n * 512);
        }
        #pragma unroll
        for (int n = 0; n < 4; ++n)
          #pragma unroll
          for (int m = 0; m < 4; ++m)
            ka[m][n] = __builtin_amdgcn_mfma_f32_16x16x32_bf16(a[m], b0[n], ka[m][n], 0, 0, 0);
        if (p < 11) {
          #pragma unroll
          for (int n = 0; n < 4; ++n) b0[n] = nb[n];
        }
      }
      {
        short8 a[4];
        #pragma unroll
        for (int m = 0; m < 4; ++m) {
          int row = m * 16 + lr;
          a[m] = *(const short8*)(ldsF + ((row * 1536 + ((2 * p + 1) * 32 + lkb) * 2) ^ ((row & 7) << 4)));
        }
        short8 nb[4];
        if (p < 11) {
          #pragma unroll
          for (int n = 0; n < 4; ++n) nb[n] = *(const short8*)(bk + (2 * p + 3) * 2048 + n * 512);
        }
        #pragma unroll
        for (int n = 0; n < 4; ++n)
          #pragma unroll
          for (int m = 0; m < 4; ++m)
            ka[m][n] = __builtin_amdgcn_mfma_f32_16x16x32_bf16(a[m], b1[n], ka[m][n], 0, 0, 0);
        if (p < 11) {
          #pragma unroll
          for (int n = 0; n < 4; ++n) b1[n] = nb[n];
        }
      }
    }
  }

  // ================= gate + y1 = (1-w)*q (frees qa, ka) ======================
  float wgt[4][4];
  #pragma unroll
  for (int m = 0; m < 4; ++m) {
    #pragma unroll
    for (int r = 0; r < 4; ++r) {
      float p = 0.0f;
      #pragma unroll
      for (int n = 0; n < 4; ++n) p += qa[m][n][r] * ka[m][n][r];
      #pragma unroll
      for (int msk = 1; msk < 16; msk <<= 1) p += __shfl_xor(p, msk, 64);
      wgt[m][r] = p * 0.125f;   // 1/sqrt(64)
    }
  }
  #pragma unroll
  for (int m = 0; m < 4; ++m) {
    #pragma unroll
    for (int r = 0; r < 4; ++r) {
      float f = 1.0f - wgt[m][r];
      long grow = row0 + m * 16 + lrow4 + r;
      #pragma unroll
      for (int n = 0; n < 4; ++n) {
        int ch = wid * 64 + n * 16 + lr;
        y1[grow * 512 + ch] = f * qa[m][n][r];
      }
    }
  }

  // ================= v GEMM: K=768, 2-deep B prefetch ========================
  f32x4 va[4][4] = {};
  {
    const unsigned short* bv = wbf + 655360 + wid * 49152 + lane * 8;
    short8 b0[4], b1[4];
    #pragma unroll
    for (int n = 0; n < 4; ++n) {
      b0[n] = *(const short8*)(bv + 0 * 2048 + n * 512);
      b1[n] = *(const short8*)(bv + 1 * 2048 + n * 512);
    }
    #pragma unroll
    for (int p = 0; p < 12; ++p) {
      {
        short8 a[4];
        #pragma unroll
        for (int m = 0; m < 4; ++m) {
          int row = m * 16 + lr;
          a[m] = *(const short8*)(ldsF + ((row * 1536 + ((2 * p) * 32 + lkb) * 2) ^ ((row & 7) << 4)));
        }
        short8 nb[4];
        if (p < 11) {
          #pragma unroll
          for (int n = 0; n < 4; ++n) nb[n] = *(const short8*)(bv + (2 * p + 2) * 2048 + n * 512);
        }
        #pragma unroll
        for (int n = 0; n < 4; ++n)
          #pragma unroll
          for (int m = 0; m < 4; ++m)
            va[m][n] = __builtin_amdgcn_mfma_f32_16x16x32_bf16(a[m], b0[n], va[m][n], 0, 0, 0);
        if (p < 11) {
          #pragma unroll
          for (int n = 0; n < 4; ++n) b0[n] = nb[n];
        }
      }
      {
        short8 a[4];
        #pragma unroll
        for (int m = 0; m < 4; ++m) {
          int row = m * 16 + lr;
          a[m] = *(const short8*)(ldsF + ((row * 1536 + ((2 * p + 1) * 32 + lkb) * 2) ^ ((row & 7) << 4)));
        }
        short8 nb[4];
        if (p < 11) {
          #pragma unroll
          for (int n = 0; n < 4; ++n) nb[n] = *(const short8*)(bv + (2 * p + 3) * 2048 + n * 512);
        }
        #pragma unroll
        for (int n = 0; n < 4; ++n)
          #pragma unroll
          for (int m = 0; m < 4; ++m)
            va[m][n] = __builtin_amdgcn_mfma_f32_16x16x32_bf16(a[m], b1[n], va[m][n], 0, 0, 0);
        if (p < 11) {
          #pragma unroll
          for (int n = 0; n < 4; ++n) b1[n] = nb[n];
        }
      }
    }
  }
  #pragma unroll
  for (int m = 0; m < 4; ++m) {
    #pragma unroll
    for (int r = 0; r < 4; ++r) {
      float f = wgt[m][r];
      long grow = row0 + m * 16 + lrow4 + r;
      #pragma unroll
      for (int n = 0; n < 4; ++n) {
        int ch = wid * 64 + n * 16 + lr;
        y2[grow * 512 + ch] = f * va[m][n][r];
      }
    }
  }
}

extern "C" void kernel_launch(void* const* d_in, const int* in_sizes, int n_in,
                              void* d_out, int out_size, void* d_ws, size_t ws_size,
                              hipStream_t stream) {
  const float* x  = (const float*)d_in[0];
  const float* xf = (const float*)d_in[1];
  const float* nw = (const float*)d_in[2];
  const float* nb = (const float*)d_in[3];
  const float* tw = (const float*)d_in[4];
  const float* tb = (const float*)d_in[5];
  const float* wq = (const float*)d_in[6];
  const float* wk = (const float*)d_in[7];
  const float* wv = (const float*)d_in[8];
  unsigned short* wbf = (unsigned short*)d_ws;   // 2 MB bf16 packed weights

  cvt_weights<<<256, 256, 0, stream>>>(wq, wk, wv, wbf);
  fused_xattn<<<512, NT, 0, stream>>>(x, xf, nw, nb, tw, tb, wbf, (float*)d_out);
}

// Round 11
// 125.504 us; speedup vs baseline: 6.1656x; 1.0273x over previous
//
#include <hip/hip_runtime.h>

#define NT 512
#define MT 64   // rows per block, 1 block/CU, 8 waves, wave == head

typedef __attribute__((ext_vector_type(8))) short short8;
typedef __attribute__((ext_vector_type(4))) float f32x4;
typedef __attribute__((ext_vector_type(4))) unsigned short u16x4;

__device__ __forceinline__ unsigned short f2bf(float f) {
  unsigned int u = __builtin_bit_cast(unsigned int, f);
  u += 0x7fffu + ((u >> 16) & 1u);
  return (unsigned short)(u >> 16);
}
__device__ __forceinline__ float bf2f(unsigned short h) {
  return __builtin_bit_cast(float, ((unsigned int)h) << 16);
}

// Repack Wq (512x512), Wk (512x768), Wv (512x768) f32 -> bf16 fragments in
// MFMA operand order: frag[head][kk32][n][lane][8 shorts] -> B-fragment load
// is lane*16B contiguous: one coalesced 1KB wave load.
__global__ void cvt_weights(const float* __restrict__ wq,
                            const float* __restrict__ wk,
                            const float* __restrict__ wv,
                            unsigned short* __restrict__ o) {
  int stride = gridDim.x * blockDim.x;
  int i0 = blockIdx.x * blockDim.x + threadIdx.x;
  for (int t = i0; t < 32768; t += stride) {
    int lane = t & 63, n = (t >> 6) & 3, kk32 = (t >> 8) & 15, head = t >> 12;
    int row = head * 64 + n * 16 + (lane & 15);
    int k   = kk32 * 32 + (lane >> 4) * 8;
    const float* s = wq + (size_t)row * 512 + k;
    unsigned short* d = o + (size_t)t * 8;
    #pragma unroll
    for (int e = 0; e < 8; ++e) d[e] = f2bf(s[e]);
  }
  for (int t = i0; t < 49152; t += stride) {
    int lane = t & 63, n = (t >> 6) & 3, rem = t >> 8;
    int kk32 = rem % 24, head = rem / 24;
    int row = head * 64 + n * 16 + (lane & 15);
    int k   = kk32 * 32 + (lane >> 4) * 8;
    const float* s = wk + (size_t)row * 768 + k;
    unsigned short* d = o + 262144 + (size_t)t * 8;
    #pragma unroll
    for (int e = 0; e < 8; ++e) d[e] = f2bf(s[e]);
  }
  for (int t = i0; t < 49152; t += stride) {
    int lane = t & 63, n = (t >> 6) & 3, rem = t >> 8;
    int kk32 = rem % 24, head = rem / 24;
    int row = head * 64 + n * 16 + (lane & 15);
    int k   = kk32 * 32 + (lane >> 4) * 8;
    const float* s = wv + (size_t)row * 768 + k;
    unsigned short* d = o + 655360 + (size_t)t * 8;
    #pragma unroll
    for (int e = 0; e < 8; ++e) d[e] = f2bf(s[e]);
  }
}

// Register model (measured): VGPR + AGPR <= 256 at 2 waves/SIMD; AGPR is sized
// by the worst phase. This kernel caps AGPR at 128 (fused ka+va) by manually
// spilling qa to LDS (bf16, per-lane slots) after q GEMM, and keeps VGPR <=
// ~120 in every phase (2-row xf chunks, 1-deep q prefetch, no kv prefetch
// arrays - the fused sweep's 32 MFMA / 12 loads density covers latency).
__global__ __launch_bounds__(NT, 2)
void fused_xattn(const float* __restrict__ x, const float* __restrict__ xf,
                 const float* __restrict__ nw, const float* __restrict__ nb,
                 const float* __restrict__ tw, const float* __restrict__ tb,
                 const unsigned short* __restrict__ wbf,
                 float* __restrict__ out) {
  __shared__ __attribute__((aligned(16))) char ldsX[65536];  // x tile; reused as q store
  __shared__ __attribute__((aligned(16))) char ldsF[98304];  // xf tile
  const int tid   = threadIdx.x;
  const int lane  = tid & 63;
  const int wid   = tid >> 6;          // wave == head
  const int lr    = lane & 15;
  const int lkb   = (lane >> 4) * 8;
  const int lrow4 = (lane >> 4) * 4;

  const long row0 = (long)blockIdx.x * MT;
  float* __restrict__ y1 = out;
  float* __restrict__ y2 = out + 16777216L;

  // ================= S1: LN(x) -> ldsX, two 4-row chunks =====================
  {
    const f32x4* g4 = (const f32x4*)nw;
    const f32x4* b4 = (const f32x4*)nb;
    f32x4 g0 = g4[lane], g1 = g4[lane + 64];
    f32x4 c0 = b4[lane], c1 = b4[lane + 64];
    #pragma unroll
    for (int cch = 0; cch < 2; ++cch) {
      f32x4 t0[4], t1[4];
      #pragma unroll
      for (int j = 0; j < 4; ++j) {
        const f32x4* rp = (const f32x4*)(x + (row0 + wid + 8 * (cch * 4 + j)) * 512);
        t0[j] = rp[lane]; t1[j] = rp[lane + 64];
      }
      #pragma unroll
      for (int j = 0; j < 4; ++j) {
        f32x4 a = t0[j], b = t1[j];
        float s  = a.x + a.y + a.z + a.w + b.x + b.y + b.z + b.w;
        float s2 = a.x*a.x + a.y*a.y + a.z*a.z + a.w*a.w
                 + b.x*b.x + b.y*b.y + b.z*b.z + b.w*b.w;
        #pragma unroll
        for (int m = 1; m < 64; m <<= 1) { s += __shfl_xor(s, m, 64); s2 += __shfl_xor(s2, m, 64); }
        float mean = s * (1.0f / 512.0f);
        float var  = s2 * (1.0f / 512.0f) - mean * mean;
        float rs   = rsqrtf(var + 1e-5f);
        u16x4 o0 = { f2bf((a.x - mean) * rs * g0.x + c0.x),
                     f2bf((a.y - mean) * rs * g0.y + c0.y),
                     f2bf((a.z - mean) * rs * g0.z + c0.z),
                     f2bf((a.w - mean) * rs * g0.w + c0.w) };
        u16x4 o1 = { f2bf((b.x - mean) * rs * g1.x + c1.x),
                     f2bf((b.y - mean) * rs * g1.y + c1.y),
                     f2bf((b.z - mean) * rs * g1.z + c1.z),
                     f2bf((b.w - mean) * rs * g1.w + c1.w) };
        int r = wid + 8 * (cch * 4 + j);
        int base = r * 1024, sw = (r & 7) << 4;
        *(u16x4*)(ldsX + ((base +       lane * 8) ^ sw)) = o0;
        *(u16x4*)(ldsX + ((base + 512 + lane * 8) ^ sw)) = o1;
      }
    }
  }
  __syncthreads();   // B1: ldsX ready

  // ---- issue xf chunk-0 (2 rows, 24 regs); latency hides under q GEMM -------
  f32x4 f0[2], f1[2], f2[2];
  #pragma unroll
  for (int j = 0; j < 2; ++j) {
    const f32x4* rp = (const f32x4*)(xf + (row0 + wid + 8 * j) * 768);
    f0[j] = rp[lane]; f1[j] = rp[lane + 64]; f2[j] = rp[lane + 128];
  }

  // ================= q GEMM: K=512 from ldsX, 1-deep B prefetch ==============
  f32x4 qa[4][4] = {};
  {
    const unsigned short* bq = wbf + wid * 32768 + lane * 8;
    short8 bc[4];
    #pragma unroll
    for (int n = 0; n < 4; ++n) bc[n] = *(const short8*)(bq + n * 512);
    for (int kk = 0; kk < 16; ++kk) {
      short8 a[4];
      #pragma unroll
      for (int m = 0; m < 4; ++m) {
        int row = m * 16 + lr;
        a[m] = *(const short8*)(ldsX + ((row * 1024 + (kk * 32 + lkb) * 2) ^ ((row & 7) << 4)));
      }
      short8 bn[4];
      if (kk < 15) {
        #pragma unroll
        for (int n = 0; n < 4; ++n) bn[n] = *(const short8*)(bq + (kk + 1) * 2048 + n * 512);
      }
      #pragma unroll
      for (int n = 0; n < 4; ++n)
        #pragma unroll
        for (int m = 0; m < 4; ++m)
          qa[m][n] = __builtin_amdgcn_mfma_f32_16x16x32_bf16(a[m], bc[n], qa[m][n], 0, 0, 0);
      if (kk < 15) {
        #pragma unroll
        for (int n = 0; n < 4; ++n) bc[n] = bn[n];
      }
    }
  }

  // ---- LN(xf) helper (writes rows wid+8*(c2*2+{0,1}) of ldsF) ---------------
  const f32x4* tg4 = (const f32x4*)tw;
  const f32x4* tb4 = (const f32x4*)tb;
  f32x4 tg0 = tg4[lane], tg1 = tg4[lane + 64], tg2 = tg4[lane + 128];
  f32x4 tc0 = tb4[lane], tc1 = tb4[lane + 64], tc2 = tb4[lane + 128];

#define LNF_CHUNK(c2)                                                          \
  {                                                                            \
    _Pragma("unroll")                                                          \
    for (int j = 0; j < 2; ++j) {                                              \
      f32x4 a = f0[j], b = f1[j], c = f2[j];                                   \
      float s  = a.x + a.y + a.z + a.w + b.x + b.y + b.z + b.w                 \
               + c.x + c.y + c.z + c.w;                                        \
      float s2 = a.x*a.x + a.y*a.y + a.z*a.z + a.w*a.w                         \
               + b.x*b.x + b.y*b.y + b.z*b.z + b.w*b.w                         \
               + c.x*c.x + c.y*c.y + c.z*c.z + c.w*c.w;                        \
      _Pragma("unroll")                                                        \
      for (int m = 1; m < 64; m <<= 1) {                                       \
        s += __shfl_xor(s, m, 64); s2 += __shfl_xor(s2, m, 64);                \
      }                                                                        \
      float mean = s * (1.0f / 768.0f);                                        \
      float var  = s2 * (1.0f / 768.0f) - mean * mean;                         \
      float rs   = rsqrtf(var + 1e-5f);                                        \
      u16x4 o0 = { f2bf((a.x - mean) * rs * tg0.x + tc0.x),                    \
                   f2bf((a.y - mean) * rs * tg0.y + tc0.y),                    \
                   f2bf((a.z - mean) * rs * tg0.z + tc0.z),                    \
                   f2bf((a.w - mean) * rs * tg0.w + tc0.w) };                  \
      u16x4 o1 = { f2bf((b.x - mean) * rs * tg1.x + tc1.x),                    \
                   f2bf((b.y - mean) * rs * tg1.y + tc1.y),                    \
                   f2bf((b.z - mean) * rs * tg1.z + tc1.z),                    \
                   f2bf((b.w - mean) * rs * tg1.w + tc1.w) };                  \
      u16x4 o2 = { f2bf((c.x - mean) * rs * tg2.x + tc2.x),                    \
                   f2bf((c.y - mean) * rs * tg2.y + tc2.y),                    \
                   f2bf((c.z - mean) * rs * tg2.z + tc2.z),                    \
                   f2bf((c.w - mean) * rs * tg2.w + tc2.w) };                  \
      int r = wid + 8 * ((c2) * 2 + j);                                        \
      int base = r * 1536, sw = (r & 7) << 4;                                  \
      *(u16x4*)(ldsF + ((base +        lane * 8) ^ sw)) = o0;                  \
      *(u16x4*)(ldsF + ((base + 512  + lane * 8) ^ sw)) = o1;                  \
      *(u16x4*)(ldsF + ((base + 1024 + lane * 8) ^ sw)) = o2;                  \
    }                                                                          \
  }
#define LDF_CHUNK(c2)                                                          \
  {                                                                            \
    _Pragma("unroll")                                                          \
    for (int j = 0; j < 2; ++j) {                                              \
      const f32x4* rp = (const f32x4*)(xf + (row0 + wid + 8 * ((c2) * 2 + j)) * 768); \
      f0[j] = rp[lane]; f1[j] = rp[lane + 64]; f2[j] = rp[lane + 128];         \
    }                                                                          \
  }

  // process c0 (loaded before q GEMM), pipeline c1..c3 1-deep
  {
    f32x4 n0[2], n1[2], n2[2];
    #pragma unroll
    for (int j = 0; j < 2; ++j) {
      const f32x4* rp = (const f32x4*)(xf + (row0 + wid + 8 * (2 + j)) * 768);
      n0[j] = rp[lane]; n1[j] = rp[lane + 64]; n2[j] = rp[lane + 128];
    }
    LNF_CHUNK(0)
    #pragma unroll
    for (int j = 0; j < 2; ++j) { f0[j] = n0[j]; f1[j] = n1[j]; f2[j] = n2[j]; }
  }
  __syncthreads();   // B2a: all waves done reading ldsX -> safe to overwrite

  // ---- pack qa -> bf16 LDS (per-lane slots in ldsX region); frees qa --------
  {
    unsigned long long* q8 = (unsigned long long*)ldsX;
    #pragma unroll
    for (int m = 0; m < 4; ++m)
      #pragma unroll
      for (int n = 0; n < 4; ++n) {
        unsigned long long v =
            (unsigned long long)f2bf(qa[m][n][0])
          | ((unsigned long long)f2bf(qa[m][n][1]) << 16)
          | ((unsigned long long)f2bf(qa[m][n][2]) << 32)
          | ((unsigned long long)f2bf(qa[m][n][3]) << 48);
        q8[wid * 1024 + (m * 4 + n) * 64 + lane] = v;
      }
  }

  // ---- finish LN(xf): c1 (held), c2, c3 -------------------------------------
  {
    f32x4 n0[2], n1[2], n2[2];
    #pragma unroll
    for (int j = 0; j < 2; ++j) {
      const f32x4* rp = (const f32x4*)(xf + (row0 + wid + 8 * (4 + j)) * 768);
      n0[j] = rp[lane]; n1[j] = rp[lane + 64]; n2[j] = rp[lane + 128];
    }
    LNF_CHUNK(1)
    #pragma unroll
    for (int j = 0; j < 2; ++j) { f0[j] = n0[j]; f1[j] = n1[j]; f2[j] = n2[j]; }
    #pragma unroll
    for (int j = 0; j < 2; ++j) {
      const f32x4* rp = (const f32x4*)(xf + (row0 + wid + 8 * (6 + j)) * 768);
      n0[j] = rp[lane]; n1[j] = rp[lane + 64]; n2[j] = rp[lane + 128];
    }
    LNF_CHUNK(2)
    #pragma unroll
    for (int j = 0; j < 2; ++j) { f0[j] = n0[j]; f1[j] = n1[j]; f2[j] = n2[j]; }
    LNF_CHUNK(3)
  }
  __syncthreads();   // B2b: ldsF ready

  // ================= fused k+v sweep: K=768, 32 MFMA / 12 loads per iter =====
  f32x4 ka[4][4] = {}, va[4][4] = {};
  {
    const unsigned short* bk = wbf + 262144 + wid * 49152 + lane * 8;
    const unsigned short* bv = wbf + 655360 + wid * 49152 + lane * 8;
    for (int kk = 0; kk < 24; ++kk) {
      short8 kf[4], vf[4];
      #pragma unroll
      for (int n = 0; n < 4; ++n) {
        kf[n] = *(const short8*)(bk + kk * 2048 + n * 512);
        vf[n] = *(const short8*)(bv + kk * 2048 + n * 512);
      }
      short8 a[4];
      #pragma unroll
      for (int m = 0; m < 4; ++m) {
        int row = m * 16 + lr;
        a[m] = *(const short8*)(ldsF + ((row * 1536 + (kk * 32 + lkb) * 2) ^ ((row & 7) << 4)));
      }
      #pragma unroll
      for (int n = 0; n < 4; ++n)
        #pragma unroll
        for (int m = 0; m < 4; ++m) {
          ka[m][n] = __builtin_amdgcn_mfma_f32_16x16x32_bf16(a[m], kf[n], ka[m][n], 0, 0, 0);
          va[m][n] = __builtin_amdgcn_mfma_f32_16x16x32_bf16(a[m], vf[n], va[m][n], 0, 0, 0);
        }
    }
  }

  // ================= gate from ldsQ + ka; y1; y2 =============================
  unsigned long long q64[4][4];
  {
    const unsigned long long* q8 = (const unsigned long long*)ldsX;
    #pragma unroll
    for (int m = 0; m < 4; ++m)
      #pragma unroll
      for (int n = 0; n < 4; ++n)
        q64[m][n] = q8[wid * 1024 + (m * 4 + n) * 64 + lane];
  }
  float wgt[4][4];
  #pragma unroll
  for (int m = 0; m < 4; ++m) {
    #pragma unroll
    for (int r = 0; r < 4; ++r) {
      float p = 0.0f;
      #pragma unroll
      for (int n = 0; n < 4; ++n)
        p += bf2f((unsigned short)(q64[m][n] >> (16 * r))) * ka[m][n][r];
      #pragma unroll
      for (int msk = 1; msk < 16; msk <<= 1) p += __shfl_xor(p, msk, 64);
      wgt[m][r] = p * 0.125f;   // 1/sqrt(64)
    }
  }
  #pragma unroll
  for (int m = 0; m < 4; ++m) {
    #pragma unroll
    for (int r = 0; r < 4; ++r) {
      float f = 1.0f - wgt[m][r];
      long grow = row0 + m * 16 + lrow4 + r;
      #pragma unroll
      for (int n = 0; n < 4; ++n) {
        int ch = wid * 64 + n * 16 + lr;
        y1[grow * 512 + ch] = f * bf2f((unsigned short)(q64[m][n] >> (16 * r)));
      }
    }
  }
  #pragma unroll
  for (int m = 0; m < 4; ++m) {
    #pragma unroll
    for (int r = 0; r < 4; ++r) {
      float f = wgt[m][r];
      long grow = row0 + m * 16 + lrow4 + r;
      #pragma unroll
      for (int n = 0; n < 4; ++n) {
        int ch = wid * 64 + n * 16 + lr;
        y2[grow * 512 + ch] = f * va[m][n][r];
      }
    }
  }
#undef LNF_CHUNK
#undef LDF_CHUNK
}

extern "C" void kernel_launch(void* const* d_in, const int* in_sizes, int n_in,
                              void* d_out, int out_size, void* d_ws, size_t ws_size,
                              hipStream_t stream) {
  const float* x  = (const float*)d_in[0];
  const float* xf = (const float*)d_in[1];
  const float* nw = (const float*)d_in[2];
  const float* nb = (const float*)d_in[3];
  const float* tw = (const float*)d_in[4];
  const float* tb = (const float*)d_in[5];
  const float* wq = (const float*)d_in[6];
  const float* wk = (const float*)d_in[7];
  const float* wv = (const float*)d_in[8];
  unsigned short* wbf = (unsigned short*)d_ws;   // 2 MB bf16 packed weights

  cvt_weights<<<256, 256, 0, stream>>>(wq, wk, wv, wbf);
  fused_xattn<<<512, NT, 0, stream>>>(x, xf, nw, nb, tw, tb, wbf, (float*)d_out);
}